// Round 7
// baseline (483.515 us; speedup 1.0000x reference)
//
#include <hip/hip_runtime.h>
#include <hip/hip_cooperative_groups.h>
#include <cstddef>

namespace cg = cooperative_groups;

#define CTXDIM 256
#define RANK 8
#define KW 7
#define SCALE 0.17677669529663687f
#define NPIX 16384
#define PLANE (NPIX * 128)     // floats per fp32 qkv plane
#define HP 14
#define NHALO 196
#define LSTRIDE 36
#define SMEMF (NHALO * LSTRIDE)  // 7056 floats = 28224 B (single k/v buffer)
#define NBLK 512

typedef _Float16 half8 __attribute__((ext_vector_type(8)));
typedef float floatx4 __attribute__((ext_vector_type(4)));

struct Params {
  const float *x, *ctx, *Wqkv, *bqkv, *A, *Blora, *Vlora;
  const float *g1w, *g1b, *g2w, *g2b, *Wproj, *bproj;
  float* out;
  _Float16 *Weff16, *Wp16, *x16;
  float* qkv;
};

// ---- cal[b][r] = alpha_b * (ctx[b] @ Blora)[r]; wave b handles batch b ----
__device__ __forceinline__ void compute_cal(const Params& p, int tid,
                                            float* cal_s) {
  const int b = tid >> 6, lane = tid & 63;
  const float c0 = p.ctx[b * CTXDIM + lane];
  const float c1 = p.ctx[b * CTXDIM + 64 + lane];
  const float c2 = p.ctx[b * CTXDIM + 128 + lane];
  const float c3 = p.ctx[b * CTXDIM + 192 + lane];
  float cp[RANK];
#pragma unroll
  for (int r = 0; r < RANK; ++r) {
    float q = c0 * p.Blora[lane * RANK + r] + c1 * p.Blora[(64 + lane) * RANK + r] +
              c2 * p.Blora[(128 + lane) * RANK + r] + c3 * p.Blora[(192 + lane) * RANK + r];
#pragma unroll
    for (int s = 32; s; s >>= 1) q += __shfl_xor(q, s, 64);
    cp[r] = q;
  }
  float gacc = 0.f;
#pragma unroll
  for (int h = 0; h < 16; ++h) {
    float q = c0 * p.g1w[h * CTXDIM + lane] + c1 * p.g1w[h * CTXDIM + 64 + lane] +
              c2 * p.g1w[h * CTXDIM + 128 + lane] + c3 * p.g1w[h * CTXDIM + 192 + lane];
#pragma unroll
    for (int s = 32; s; s >>= 1) q += __shfl_xor(q, s, 64);
    gacc += fmaxf(q + p.g1b[h], 0.f) * p.g2w[h];
  }
  if (lane == 0) {
    const float alpha = 1.f / (1.f + __expf(-(gacc + p.g2b[0])));
#pragma unroll
    for (int r = 0; r < RANK; ++r) cal_s[b * RANK + r] = alpha * cp[r];
  }
}

// ---- Phase A task: fold Weff16 (0..767) | Wproj cvt (768..831) | x cvt ----
__device__ __forceinline__ void phaseA_task(const Params& p, int task, int tid,
                                            const float* cal_s) {
  if (task < 768) {
    const int b = task / 192;
    const int ob = task - b * 192;
    const int o = ob * 2 + (tid >> 7);
    const int k = tid & 127;
    const float4 a0 = *(const float4*)&p.A[k * RANK];
    const float4 a1 = *(const float4*)&p.A[k * RANK + 4];
    const float4 v0 = *(const float4*)&p.Vlora[o * RANK];
    const float4 v1 = *(const float4*)&p.Vlora[o * RANK + 4];
    const float* cb = &cal_s[b * RANK];
    float d = a0.x * v0.x * cb[0];
    d = fmaf(a0.y * v0.y, cb[1], d);
    d = fmaf(a0.z * v0.z, cb[2], d);
    d = fmaf(a0.w * v0.w, cb[3], d);
    d = fmaf(a1.x * v1.x, cb[4], d);
    d = fmaf(a1.y * v1.y, cb[5], d);
    d = fmaf(a1.z * v1.z, cb[6], d);
    d = fmaf(a1.w * v1.w, cb[7], d);
    p.Weff16[((size_t)b * 384 + o) * 128 + k] = (_Float16)(p.Wqkv[o * 128 + k] + d);
  } else if (task < 832) {
    const int i = (task - 768) * 256 + tid;
    p.Wp16[i] = (_Float16)p.Wproj[i];
  } else {
    const size_t i = ((size_t)(task - 832) * 256 + tid) * 8;
    const float4 a = *(const float4*)(p.x + i);
    const float4 b4 = *(const float4*)(p.x + i + 4);
    half8 o8;
    o8[0] = (_Float16)a.x; o8[1] = (_Float16)a.y;
    o8[2] = (_Float16)a.z; o8[3] = (_Float16)a.w;
    o8[4] = (_Float16)b4.x; o8[5] = (_Float16)b4.y;
    o8[6] = (_Float16)b4.z; o8[7] = (_Float16)b4.w;
    *(half8*)(p.x16 + i) = o8;
  }
}

// ---- 64x64 fp16 MFMA GEMM tile, K=128, no LDS (m89/m118-verified maps) ----
__device__ __forceinline__ void gemm64x64(
    const _Float16* Ap, const _Float16* Bp, const float* bias,
    float* C, int plane, int m0, int n0, int tid) {
  const int lane = tid & 63;
  const int w = tid >> 6;
  const int r = lane & 15;
  const int quad = lane >> 4;

  const _Float16* ap = Ap + (size_t)(m0 + w * 16 + r) * 128 + quad * 8;
  const _Float16* bp = Bp + (size_t)(n0 + r) * 128 + quad * 8;

  floatx4 acc0 = {0.f, 0.f, 0.f, 0.f};
  floatx4 acc1 = acc0, acc2 = acc0, acc3 = acc0;
#pragma unroll
  for (int kc = 0; kc < 4; ++kc) {
    const half8 a  = *(const half8*)(ap + kc * 32);
    const half8 b0 = *(const half8*)(bp + kc * 32);
    const half8 b1 = *(const half8*)(bp + 16 * 128 + kc * 32);
    const half8 b2 = *(const half8*)(bp + 32 * 128 + kc * 32);
    const half8 b3 = *(const half8*)(bp + 48 * 128 + kc * 32);
    acc0 = __builtin_amdgcn_mfma_f32_16x16x32_f16(a, b0, acc0, 0, 0, 0);
    acc1 = __builtin_amdgcn_mfma_f32_16x16x32_f16(a, b1, acc1, 0, 0, 0);
    acc2 = __builtin_amdgcn_mfma_f32_16x16x32_f16(a, b2, acc2, 0, 0, 0);
    acc3 = __builtin_amdgcn_mfma_f32_16x16x32_f16(a, b3, acc3, 0, 0, 0);
  }

  const int mbase = m0 + w * 16 + quad * 4;
  floatx4 accs[4] = {acc0, acc1, acc2, acc3};
#pragma unroll
  for (int nt = 0; nt < 4; ++nt) {
    const int n = n0 + nt * 16 + r;
    const float bv = bias[n];
    float* cp = C + (size_t)(n >> 7) * plane + (size_t)mbase * 128 + (n & 127);
#pragma unroll
    for (int reg = 0; reg < 4; ++reg)
      cp[(size_t)reg * 128] = accs[nt][reg] + bv;
  }
}

__device__ __forceinline__ void phaseB_task(const Params& p, int task, int tid) {
  const int bx = task & 63;
  const int rest = task >> 6;
  const int by = rest % 6;
  const int z = rest / 6;
  gemm64x64(p.x16, p.Weff16 + (size_t)z * 384 * 128, p.bqkv,
            p.qkv, PLANE, bx * 64 + z * 4096, by * 64, tid);
}

// ---- attention tile, two-pass staging through ONE 28.2 KB LDS buffer ----
// Caller must __syncthreads() before calling (protects sm from prev tile).
__device__ __forceinline__ void attn_task(const Params& p, int task, int tid,
                                          float* sm) {
  const int h = task & 3;
  const int tj = (task >> 2) & 7;
  const int ti = (task >> 5) & 7;
  const int b = task >> 8;
  const int i0 = ti * 8 - 3;
  const int j0 = tj * 8 - 3;

  // staging addresses, computed once, reused for K and V passes
  int lofs[7], gofs[7];
#pragma unroll
  for (int r = 0; r < 7; ++r) {
    const int f4 = tid + r * 256;
    lofs[r] = -1; gofs[r] = -1;
    if (f4 < NHALO * 8) {
      const int pp = f4 >> 3;
      const int d = (f4 & 7) * 4;
      const int hr = pp / HP;
      const int hc = pp - hr * HP;
      const int ii = i0 + hr;
      const int jj = j0 + hc;
      lofs[r] = pp * LSTRIDE + d;
      if ((unsigned)ii < 64u && (unsigned)jj < 64u)
        gofs[r] = (b * 4096 + ii * 64 + jj) * 128 + h * 32 + d;
    }
  }

  const int pix = tid >> 2;
  const int qq = tid & 3;
  const int pi = pix >> 3;
  const int pj = pix & 7;
  const int n = b * 4096 + (ti * 8 + pi) * 64 + (tj * 8 + pj);
  const int dbase = qq * 8;

  float q[8];
  {
    const float* qp = p.qkv + (size_t)n * 128 + h * 32 + dbase;
    const float4 a = *(const float4*)qp;
    const float4 c = *(const float4*)(qp + 4);
    q[0] = a.x; q[1] = a.y; q[2] = a.z; q[3] = a.w;
    q[4] = c.x; q[5] = c.y; q[6] = c.z; q[7] = c.w;
  }

  // ---- pass 1: stage K ----
  const float* kpl = p.qkv + PLANE;
#pragma unroll
  for (int r = 0; r < 7; ++r) {
    if (lofs[r] >= 0) {
      float4 kv = make_float4(0.f, 0.f, 0.f, 0.f);
      if (gofs[r] >= 0) kv = *(const float4*)(kpl + gofs[r]);
      *(float4*)&sm[lofs[r]] = kv;
    }
  }
  __syncthreads();

  float l[49];
#pragma unroll
  for (int di = 0; di < KW; ++di) {
#pragma unroll
    for (int dj = 0; dj < KW; ++dj) {
      const int hp = (pi + di) * HP + (pj + dj);
      const float* kp = &sm[hp * LSTRIDE + dbase];
      const float4 a = *(const float4*)kp;
      const float4 c = *(const float4*)(kp + 4);
      float pr = q[0] * a.x + q[1] * a.y + q[2] * a.z + q[3] * a.w +
                 q[4] * c.x + q[5] * c.y + q[6] * c.z + q[7] * c.w;
      pr += __shfl_xor(pr, 1, 64);
      pr += __shfl_xor(pr, 2, 64);
      l[di * KW + dj] = pr * SCALE;
    }
  }

  float mx = l[0];
#pragma unroll
  for (int s = 1; s < 49; ++s) mx = fmaxf(mx, l[s]);
  float sum = 0.f;
#pragma unroll
  for (int s = 0; s < 49; ++s) {
    const float w = __expf(l[s] - mx);
    l[s] = w;
    sum += w;
  }
  const float inv = 1.f / sum;
  __syncthreads();   // done reading K from sm

  // ---- pass 2: stage V into the same buffer ----
  const float* vpl = p.qkv + 2 * (size_t)PLANE;
#pragma unroll
  for (int r = 0; r < 7; ++r) {
    if (lofs[r] >= 0) {
      float4 vv = make_float4(0.f, 0.f, 0.f, 0.f);
      if (gofs[r] >= 0) vv = *(const float4*)(vpl + gofs[r]);
      *(float4*)&sm[lofs[r]] = vv;
    }
  }
  __syncthreads();

  float o[8] = {0.f, 0.f, 0.f, 0.f, 0.f, 0.f, 0.f, 0.f};
#pragma unroll
  for (int di = 0; di < KW; ++di) {
#pragma unroll
    for (int dj = 0; dj < KW; ++dj) {
      const int hp = (pi + di) * HP + (pj + dj);
      const float w = l[di * KW + dj];
      const float* vp = &sm[hp * LSTRIDE + dbase];
      const float4 a = *(const float4*)vp;
      const float4 c = *(const float4*)(vp + 4);
      o[0] = fmaf(w, a.x, o[0]); o[1] = fmaf(w, a.y, o[1]);
      o[2] = fmaf(w, a.z, o[2]); o[3] = fmaf(w, a.w, o[3]);
      o[4] = fmaf(w, c.x, o[4]); o[5] = fmaf(w, c.y, o[5]);
      o[6] = fmaf(w, c.z, o[6]); o[7] = fmaf(w, c.w, o[7]);
    }
  }

  half8 ov;
  ov[0] = (_Float16)(o[0] * inv); ov[1] = (_Float16)(o[1] * inv);
  ov[2] = (_Float16)(o[2] * inv); ov[3] = (_Float16)(o[3] * inv);
  ov[4] = (_Float16)(o[4] * inv); ov[5] = (_Float16)(o[5] * inv);
  ov[6] = (_Float16)(o[6] * inv); ov[7] = (_Float16)(o[7] * inv);
  *(half8*)(p.x16 + (size_t)n * 128 + h * 32 + dbase) = ov;
}

// ---------------------------------------------------------------------------
// Cooperative fused kernel: 4 phases over NBLK persistent blocks.
// LDS = 28224 + 128 B -> >=2 blocks/CU even under a 64 KB occupancy model,
// so cooperative capacity >= 512 covers grid 512.
// ---------------------------------------------------------------------------
__global__ __launch_bounds__(256, 2) void fused_kernel(Params p) {
  __shared__ __align__(16) float sm[SMEMF];
  __shared__ float cal_s[32];
  const int tid = threadIdx.x;
  const int nb = gridDim.x;
  cg::grid_group grid = cg::this_grid();

  compute_cal(p, tid, cal_s);
  __syncthreads();
  for (int task = blockIdx.x; task < 1856; task += nb)
    phaseA_task(p, task, tid, cal_s);
  __threadfence();
  grid.sync();

  for (int task = blockIdx.x; task < 1536; task += nb)
    phaseB_task(p, task, tid);
  __threadfence();
  grid.sync();

  for (int task = blockIdx.x; task < 1024; task += nb) {
    __syncthreads();
    attn_task(p, task, tid, sm);
  }
  __threadfence();
  grid.sync();

  for (int task = blockIdx.x; task < 512; task += nb)
    gemm64x64(p.x16, p.Wp16, p.bproj, p.out, 0, (task >> 1) * 64,
              (task & 1) * 64, tid);
}

// ---------------------------------------------------------------------------
// Fallback path: same device functions as ordinary kernels (bit-identical
// output), used iff the cooperative launch is rejected by the runtime.
// ---------------------------------------------------------------------------
__global__ __launch_bounds__(256) void prep_kernel(Params p) {
  __shared__ float cal_s[32];
  compute_cal(p, threadIdx.x, cal_s);
  __syncthreads();
  for (int task = blockIdx.x; task < 1856; task += gridDim.x)
    phaseA_task(p, task, threadIdx.x, cal_s);
}
__global__ __launch_bounds__(256) void gemm1_kernel(Params p) {
  for (int task = blockIdx.x; task < 1536; task += gridDim.x)
    phaseB_task(p, task, threadIdx.x);
}__global__ __launch_bounds__(256) void attn_kernel(Params p) {
  __shared__ __align__(16) float sm[SMEMF];
  for (int task = blockIdx.x; task < 1024; task += gridDim.x) {
    __syncthreads();
    attn_task(p, task, threadIdx.x, sm);
  }
}
__global__ __launch_bounds__(256) void gemm2_kernel(Params p) {
  for (int task = blockIdx.x; task < 512; task += gridDim.x)
    gemm64x64(p.x16, p.Wp16, p.bproj, p.out, 0, (task >> 1) * 64,
              (task & 1) * 64, threadIdx.x);
}

// ---------------------------------------------------------------------------
// Workspace (29 MB):
//   [4 KB, 388 KB)   Weff16  [4][384][128] fp16
//   [448 KB, 480 KB) Wp16    [128][128] fp16
//   [1 MB, 5 MB)     x16     [16384][128] fp16 (reused as attn fp16 output)
//   [5 MB, 29 MB)    qkv     [3][16384][128] fp32 planar
// ---------------------------------------------------------------------------
extern "C" void kernel_launch(void* const* d_in, const int* in_sizes, int n_in,
                              void* d_out, int out_size, void* d_ws, size_t ws_size,
                              hipStream_t stream) {
  char* ws = (char*)d_ws;
  Params hp;
  hp.x     = (const float*)d_in[0];
  hp.ctx   = (const float*)d_in[1];
  hp.Wqkv  = (const float*)d_in[2];
  hp.bqkv  = (const float*)d_in[3];
  hp.A     = (const float*)d_in[4];
  hp.Blora = (const float*)d_in[5];
  hp.Vlora = (const float*)d_in[6];
  hp.g1w   = (const float*)d_in[7];
  hp.g1b   = (const float*)d_in[8];
  hp.g2w   = (const float*)d_in[9];
  hp.g2b   = (const float*)d_in[10];
  hp.Wproj = (const float*)d_in[11];
  hp.bproj = (const float*)d_in[12];
  hp.out   = (float*)d_out;
  hp.Weff16 = (_Float16*)(ws + (4u << 10));
  hp.Wp16   = (_Float16*)(ws + (448u << 10));
  hp.x16    = (_Float16*)(ws + (1u << 20));
  hp.qkv    = (float*)(ws + (5u << 20));

  void* args[] = {&hp};
  hipError_t err = hipLaunchCooperativeKernel(
      (const void*)fused_kernel, dim3(NBLK), dim3(256), args, 0, stream);
  if (err != hipSuccess) {
    // Deterministic fallback (environment-determined, not call-dependent):
    // identical device functions => bit-identical results.
    prep_kernel<<<1856, 256, 0, stream>>>(hp);
    gemm1_kernel<<<1536, 256, 0, stream>>>(hp);
    attn_kernel<<<1024, 256, 0, stream>>>(hp);
    gemm2_kernel<<<512, 256, 0, stream>>>(hp);
  }
}

// Round 8
// 138.785 us; speedup vs baseline: 3.4839x; 3.4839x over previous
//
#include <hip/hip_runtime.h>
#include <cstddef>

#define CTXDIM 256
#define RANK 8
#define KW 7
#define SCALE 0.17677669529663687f
#define NPIX 16384
#define PLANE (NPIX * 128)     // floats per fp32 qkv plane
#define HP 14
#define NHALO 196
#define LSTRIDE 36
#define WSTRIDE 136            // fp16 LDS tile stride: b128 frag reads 2-way banks

typedef _Float16 half8 __attribute__((ext_vector_type(8)));
typedef float floatx4 __attribute__((ext_vector_type(4)));

struct Params {
  const float *x, *ctx, *Wqkv, *bqkv, *A, *Blora, *Vlora;
  const float *g1w, *g1b, *g2w, *g2b, *Wproj, *bproj;
  float* out;
  _Float16* at16;   // attention output, fp16 [N][128]
  float* qkv;       // planar fp32 [3][N][128]
};

// ---- cal[b][r] = alpha_b * (ctx[b] @ Blora)[r]; wave b handles batch b ----
__device__ __forceinline__ void compute_cal(const Params& p, int tid,
                                            float* cal_s) {
  const int b = tid >> 6, lane = tid & 63;
  const float c0 = p.ctx[b * CTXDIM + lane];
  const float c1 = p.ctx[b * CTXDIM + 64 + lane];
  const float c2 = p.ctx[b * CTXDIM + 128 + lane];
  const float c3 = p.ctx[b * CTXDIM + 192 + lane];
  float cp[RANK];
#pragma unroll
  for (int r = 0; r < RANK; ++r) {
    float q = c0 * p.Blora[lane * RANK + r] + c1 * p.Blora[(64 + lane) * RANK + r] +
              c2 * p.Blora[(128 + lane) * RANK + r] + c3 * p.Blora[(192 + lane) * RANK + r];
#pragma unroll
    for (int s = 32; s; s >>= 1) q += __shfl_xor(q, s, 64);
    cp[r] = q;
  }
  float gacc = 0.f;
#pragma unroll
  for (int h = 0; h < 16; ++h) {
    float q = c0 * p.g1w[h * CTXDIM + lane] + c1 * p.g1w[h * CTXDIM + 64 + lane] +
              c2 * p.g1w[h * CTXDIM + 128 + lane] + c3 * p.g1w[h * CTXDIM + 192 + lane];
#pragma unroll
    for (int s = 32; s; s >>= 1) q += __shfl_xor(q, s, 64);
    gacc += fmaxf(q + p.g1b[h], 0.f) * p.g2w[h];
  }
  if (lane == 0) {
    const float alpha = 1.f / (1.f + __expf(-(gacc + p.g2b[0])));
#pragma unroll
    for (int r = 0; r < RANK; ++r) cal_s[b * RANK + r] = alpha * cp[r];
  }
}

// ---- stage 64 fp32 rows (row stride 128) -> LDS fp16 [64][WSTRIDE] ----
// thread t: row = t>>2, col block = (t&3)*32.  2-way LDS bank writes (free).
__device__ __forceinline__ void stage_rows_f16(const float* __restrict__ src,
                                               _Float16* dst, int tid) {
  const int row = tid >> 2;
  const int c0 = (tid & 3) * 32;
  const float* sp = src + (size_t)row * 128 + c0;
  _Float16* dp = dst + row * WSTRIDE + c0;
#pragma unroll
  for (int i = 0; i < 4; ++i) {
    const float4 a = *(const float4*)(sp + i * 8);
    const float4 b = *(const float4*)(sp + i * 8 + 4);
    half8 o;
    o[0] = (_Float16)a.x; o[1] = (_Float16)a.y;
    o[2] = (_Float16)a.z; o[3] = (_Float16)a.w;
    o[4] = (_Float16)b.x; o[5] = (_Float16)b.y;
    o[6] = (_Float16)b.z; o[7] = (_Float16)b.w;
    *(half8*)(dp + i * 8) = o;
  }
}

// ---- 64x64 MFMA tile from LDS fp16 tiles (stride WSTRIDE), K=128 ----
// Fragment maps (m89/m118-verified): A[m=lane&15][k=quad*8+j],
// B[k][n=lane&15], D col=lane&15, row=quad*4+reg.
// C written planar fp32: addr = (ncol>>7)*plane + m*128 + (ncol&127).
__device__ __forceinline__ void mfma_tile_lds(
    const _Float16* xs, const _Float16* ws, const float* bias, int biasofs,
    float* C, int plane, int mbase0, int tid) {
  const int lane = tid & 63;
  const int w = tid >> 6;
  const int r = lane & 15;
  const int quad = lane >> 4;

  const _Float16* ap = xs + (w * 16 + r) * WSTRIDE + quad * 8;
  const _Float16* bp = ws + r * WSTRIDE + quad * 8;

  floatx4 acc0 = {0.f, 0.f, 0.f, 0.f};
  floatx4 acc1 = acc0, acc2 = acc0, acc3 = acc0;
#pragma unroll
  for (int kc = 0; kc < 4; ++kc) {
    const half8 a  = *(const half8*)(ap + kc * 32);
    const half8 b0 = *(const half8*)(bp + kc * 32);
    const half8 b1 = *(const half8*)(bp + 16 * WSTRIDE + kc * 32);
    const half8 b2 = *(const half8*)(bp + 32 * WSTRIDE + kc * 32);
    const half8 b3 = *(const half8*)(bp + 48 * WSTRIDE + kc * 32);
    acc0 = __builtin_amdgcn_mfma_f32_16x16x32_f16(a, b0, acc0, 0, 0, 0);
    acc1 = __builtin_amdgcn_mfma_f32_16x16x32_f16(a, b1, acc1, 0, 0, 0);
    acc2 = __builtin_amdgcn_mfma_f32_16x16x32_f16(a, b2, acc2, 0, 0, 0);
    acc3 = __builtin_amdgcn_mfma_f32_16x16x32_f16(a, b3, acc3, 0, 0, 0);
  }

  const int mbase = mbase0 + w * 16 + quad * 4;
  floatx4 accs[4] = {acc0, acc1, acc2, acc3};
#pragma unroll
  for (int nt = 0; nt < 4; ++nt) {
    const int ncol = biasofs + nt * 16 + r;
    const float bv = bias[ncol];
    float* cp = C + (size_t)(ncol >> 7) * plane + (size_t)mbase * 128 + (ncol & 127);
#pragma unroll
    for (int reg = 0; reg < 4; ++reg)
      cp[(size_t)reg * 128] = accs[nt][reg] + bv;
  }
}

// ---------------------------------------------------------------------------
// K1: QKV GEMM with block-local prep.  Block (bx, by, z):
//   m-rows  = z*4096 + bx*64 .. +63   (pixels of batch z)
//   n-cols  = by*64 .. +63 of the 384 qkv outputs
// cal computed redundantly; Weff rows folded into LDS fp16; x rows converted
// into LDS fp16; then 64x64 MFMA.  qkv bit-identical to the R5 pipeline.
// ---------------------------------------------------------------------------
__global__ __launch_bounds__(256) void gemm1_kernel(Params p) {
  __shared__ __align__(16) _Float16 xs[64 * WSTRIDE];
  __shared__ __align__(16) _Float16 wsh[64 * WSTRIDE];
  __shared__ float cal_s[32];
  const int tid = threadIdx.x;
  const int bx = blockIdx.x, by = blockIdx.y, z = blockIdx.z;
  const int m0 = z * 4096 + bx * 64;
  const int n0 = by * 64;

  compute_cal(p, tid, cal_s);
  stage_rows_f16(p.x + (size_t)m0 * 128, xs, tid);
  __syncthreads();   // cal_s visible for fold

  // fold Weff rows n0..n0+63 of batch z into wsh (fp16)
  {
    const int k = tid & 127;
    const int half = tid >> 7;              // 0..1 -> rows half*32..+31
    const float4 a0 = *(const float4*)&p.A[k * RANK];
    const float4 a1 = *(const float4*)&p.A[k * RANK + 4];
    const float* cb = &cal_s[z * RANK];
    const float c0 = cb[0], c1 = cb[1], c2 = cb[2], c3 = cb[3];
    const float c4 = cb[4], c5 = cb[5], c6 = cb[6], c7 = cb[7];
#pragma unroll
    for (int rr = 0; rr < 32; ++rr) {
      const int row = half * 32 + rr;       // local row, global o = n0+row
      const int o = n0 + row;
      const float4 v0 = *(const float4*)&p.Vlora[o * RANK];
      const float4 v1 = *(const float4*)&p.Vlora[o * RANK + 4];
      float d = a0.x * v0.x * c0;
      d = fmaf(a0.y * v0.y, c1, d);
      d = fmaf(a0.z * v0.z, c2, d);
      d = fmaf(a0.w * v0.w, c3, d);
      d = fmaf(a1.x * v1.x, c4, d);
      d = fmaf(a1.y * v1.y, c5, d);
      d = fmaf(a1.z * v1.z, c6, d);
      d = fmaf(a1.w * v1.w, c7, d);
      wsh[row * WSTRIDE + k] = (_Float16)(p.Wqkv[o * 128 + k] + d);
    }
  }
  __syncthreads();

  mfma_tile_lds(xs, wsh, p.bqkv, n0, p.qkv, PLANE, m0, tid);
}

// ---------------------------------------------------------------------------
// K2: neighborhood attention (R5 verbatim).  Block = (batch, 8x8 tile, head);
// 14x14 fp32 k/v halo in LDS (zero-fill OOB = reference zero-pad softmax
// semantics); 4 threads/pixel; output fp16 [N][128].
// ---------------------------------------------------------------------------
__global__ __launch_bounds__(256) void attn_kernel(Params p) {
  __shared__ __align__(16) float ks[NHALO * LSTRIDE];
  __shared__ __align__(16) float vs[NHALO * LSTRIDE];

  const int bid = blockIdx.x;
  const int h = bid & 3;
  const int tj = (bid >> 2) & 7;
  const int ti = (bid >> 5) & 7;
  const int b = bid >> 8;
  const int t = threadIdx.x;

  const float* kpl = p.qkv + PLANE;
  const float* vpl = p.qkv + 2 * (size_t)PLANE;

  const int i0 = ti * 8 - 3;
  const int j0 = tj * 8 - 3;
#pragma unroll
  for (int r = 0; r < 7; ++r) {
    const int f4 = t + r * 256;
    if (f4 < NHALO * 8) {
      const int pp = f4 >> 3;
      const int d = (f4 & 7) * 4;
      const int hr = pp / HP;
      const int hc = pp - hr * HP;
      const int ii = i0 + hr;
      const int jj = j0 + hc;
      float4 kv = make_float4(0.f, 0.f, 0.f, 0.f);
      float4 vv = make_float4(0.f, 0.f, 0.f, 0.f);
      if ((unsigned)ii < 64u && (unsigned)jj < 64u) {
        const size_t gbase = (size_t)(b * 4096 + ii * 64 + jj) * 128 + h * 32 + d;
        kv = *(const float4*)(kpl + gbase);
        vv = *(const float4*)(vpl + gbase);
      }
      *(float4*)&ks[pp * LSTRIDE + d] = kv;
      *(float4*)&vs[pp * LSTRIDE + d] = vv;
    }
  }
  __syncthreads();

  const int pix = t >> 2;
  const int qq = t & 3;
  const int pi = pix >> 3;
  const int pj = pix & 7;
  const int n = b * 4096 + (ti * 8 + pi) * 64 + (tj * 8 + pj);
  const int dbase = qq * 8;

  float q[8];
  {
    const float* qp = p.qkv + (size_t)n * 128 + h * 32 + dbase;
    const float4 a = *(const float4*)qp;
    const float4 c = *(const float4*)(qp + 4);
    q[0] = a.x; q[1] = a.y; q[2] = a.z; q[3] = a.w;
    q[4] = c.x; q[5] = c.y; q[6] = c.z; q[7] = c.w;
  }

  float l[49];
#pragma unroll
  for (int di = 0; di < KW; ++di) {
#pragma unroll
    for (int dj = 0; dj < KW; ++dj) {
      const int hp = (pi + di) * HP + (pj + dj);
      const float* kp = &ks[hp * LSTRIDE + dbase];
      const float4 a = *(const float4*)kp;
      const float4 c = *(const float4*)(kp + 4);
      float pr = q[0] * a.x + q[1] * a.y + q[2] * a.z + q[3] * a.w +
                 q[4] * c.x + q[5] * c.y + q[6] * c.z + q[7] * c.w;
      pr += __shfl_xor(pr, 1, 64);
      pr += __shfl_xor(pr, 2, 64);
      l[di * KW + dj] = pr * SCALE;
    }
  }

  float mx = l[0];
#pragma unroll
  for (int s = 1; s < 49; ++s) mx = fmaxf(mx, l[s]);
  float sum = 0.f;
#pragma unroll
  for (int s = 0; s < 49; ++s) {
    const float w = __expf(l[s] - mx);
    l[s] = w;
    sum += w;
  }
  const float inv = 1.f / sum;

  float o[8] = {0.f, 0.f, 0.f, 0.f, 0.f, 0.f, 0.f, 0.f};
#pragma unroll
  for (int di = 0; di < KW; ++di) {
#pragma unroll
    for (int dj = 0; dj < KW; ++dj) {
      const int hp = (pi + di) * HP + (pj + dj);
      const float w = l[di * KW + dj];
      const float* vp = &vs[hp * LSTRIDE + dbase];
      const float4 a = *(const float4*)vp;
      const float4 c = *(const float4*)(vp + 4);
      o[0] = fmaf(w, a.x, o[0]); o[1] = fmaf(w, a.y, o[1]);
      o[2] = fmaf(w, a.z, o[2]); o[3] = fmaf(w, a.w, o[3]);
      o[4] = fmaf(w, c.x, o[4]); o[5] = fmaf(w, c.y, o[5]);
      o[6] = fmaf(w, c.z, o[6]); o[7] = fmaf(w, c.w, o[7]);
    }
  }

  half8 ov;
  ov[0] = (_Float16)(o[0] * inv); ov[1] = (_Float16)(o[1] * inv);
  ov[2] = (_Float16)(o[2] * inv); ov[3] = (_Float16)(o[3] * inv);
  ov[4] = (_Float16)(o[4] * inv); ov[5] = (_Float16)(o[5] * inv);
  ov[6] = (_Float16)(o[6] * inv); ov[7] = (_Float16)(o[7] * inv);
  *(half8*)(p.at16 + (size_t)n * 128 + h * 32 + dbase) = ov;
}

// ---------------------------------------------------------------------------
// K3: projection GEMM with block-local Wproj->fp16.  Block (bx, by):
// rows bx*64..+63 of attnout (fp16, global), cols by*64..+63 of out.
// ---------------------------------------------------------------------------
__global__ __launch_bounds__(256) void gemm2_kernel(Params p) {
  __shared__ __align__(16) _Float16 wsh[64 * WSTRIDE];
  const int tid = threadIdx.x;
  const int m0 = blockIdx.x * 64;
  const int n0 = blockIdx.y * 64;

  stage_rows_f16(p.Wproj + (size_t)n0 * 128, wsh, tid);
  __syncthreads();

  // A fragments straight from global fp16 (as the R5 gemm); B from LDS.
  const int lane = tid & 63;
  const int w = tid >> 6;
  const int r = lane & 15;
  const int quad = lane >> 4;
  const _Float16* ap = p.at16 + (size_t)(m0 + w * 16 + r) * 128 + quad * 8;
  const _Float16* bp = wsh + r * WSTRIDE + quad * 8;

  floatx4 acc0 = {0.f, 0.f, 0.f, 0.f};
  floatx4 acc1 = acc0, acc2 = acc0, acc3 = acc0;
#pragma unroll
  for (int kc = 0; kc < 4; ++kc) {
    const half8 a  = *(const half8*)(ap + kc * 32);
    const half8 b0 = *(const half8*)(bp + kc * 32);
    const half8 b1 = *(const half8*)(bp + 16 * WSTRIDE + kc * 32);
    const half8 b2 = *(const half8*)(bp + 32 * WSTRIDE + kc * 32);
    const half8 b3 = *(const half8*)(bp + 48 * WSTRIDE + kc * 32);
    acc0 = __builtin_amdgcn_mfma_f32_16x16x32_f16(a, b0, acc0, 0, 0, 0);
    acc1 = __builtin_amdgcn_mfma_f32_16x16x32_f16(a, b1, acc1, 0, 0, 0);
    acc2 = __builtin_amdgcn_mfma_f32_16x16x32_f16(a, b2, acc2, 0, 0, 0);
    acc3 = __builtin_amdgcn_mfma_f32_16x16x32_f16(a, b3, acc3, 0, 0, 0);
  }

  const int mbase = m0 + w * 16 + quad * 4;
  floatx4 accs[4] = {acc0, acc1, acc2, acc3};
#pragma unroll
  for (int nt = 0; nt < 4; ++nt) {
    const int n = n0 + nt * 16 + r;
    const float bv = p.bproj[n];
    float* cp = p.out + (size_t)mbase * 128 + n;
#pragma unroll
    for (int reg = 0; reg < 4; ++reg)
      cp[(size_t)reg * 128] = accs[nt][reg] + bv;
  }
}

// ---------------------------------------------------------------------------
// Workspace (29 MB):
//   [1 MB, 5 MB)   at16  [16384][128] fp16  (attention output)
//   [5 MB, 29 MB)  qkv   [3][16384][128] fp32 planar
// ---------------------------------------------------------------------------
extern "C" void kernel_launch(void* const* d_in, const int* in_sizes, int n_in,
                              void* d_out, int out_size, void* d_ws, size_t ws_size,
                              hipStream_t stream) {
  char* ws = (char*)d_ws;
  Params hp;
  hp.x     = (const float*)d_in[0];
  hp.ctx   = (const float*)d_in[1];
  hp.Wqkv  = (const float*)d_in[2];
  hp.bqkv  = (const float*)d_in[3];
  hp.A     = (const float*)d_in[4];
  hp.Blora = (const float*)d_in[5];
  hp.Vlora = (const float*)d_in[6];
  hp.g1w   = (const float*)d_in[7];
  hp.g1b   = (const float*)d_in[8];
  hp.g2w   = (const float*)d_in[9];
  hp.g2b   = (const float*)d_in[10];
  hp.Wproj = (const float*)d_in[11];
  hp.bproj = (const float*)d_in[12];
  hp.out   = (float*)d_out;
  hp.at16  = (_Float16*)(ws + (1u << 20));
  hp.qkv   = (float*)(ws + (5u << 20));

  gemm1_kernel<<<dim3(64, 6, 4), 256, 0, stream>>>(hp);
  attn_kernel<<<1024, 256, 0, stream>>>(hp);
  gemm2_kernel<<<dim3(256, 2), 256, 0, stream>>>(hp);
}